// Round 1
// baseline (880.109 us; speedup 1.0000x reference)
//
#include <hip/hip_runtime.h>

#define EDIM 128
#define MDIM 8
#define ADIM 64
#define NFR  50

__device__ __forceinline__ float waveReduceSum(float v) {
    #pragma unroll
    for (int s = 32; s >= 1; s >>= 1) v += __shfl_xor(v, s, 64);
    return v;
}

// Kernel 1: att_key[b,f,m] = sum_e (uid_n * fe_n)[e] * Key[e,m]
__global__ __launch_bounds__(128)
void k1_attkey(const int* __restrict__ input_u,
               const int* __restrict__ input_uf,
               const float* __restrict__ uidW,
               const float* __restrict__ Key,
               float* __restrict__ att_key,
               int user_num)
{
    const int b = blockIdx.x;
    const int t = threadIdx.x;      // == e
    const int wid = t >> 6;
    const int lane = t & 63;

    __shared__ float keyT[MDIM * EDIM];   // transposed: [m][e]
    __shared__ float red1[2];
    __shared__ float redm[2 * MDIM];

    for (int i = t; i < MDIM * EDIM; i += 128) {
        int m = i >> 7, e = i & 127;
        keyT[i] = Key[e * MDIM + m];
    }

    const int uidx = input_u[b];
    const float uid_e = uidW[(size_t)uidx * EDIM + t];
    float ss = waveReduceSum(uid_e * uid_e);
    if (lane == 0) red1[wid] = ss;
    __syncthreads();
    const float unorm = sqrtf(red1[0] + red1[1]);
    const float uid_n = uid_e / fmaxf(unorm, 1e-12f);

    const int* uf = input_uf + (size_t)b * NFR;
    for (int f = 0; f < NFR; ++f) {
        const int fid = uf[f];
        const float fn = (fid != user_num) ? 1.0f : 0.0f;
        const float fe = uidW[(size_t)fid * EDIM + t] * fn;
        float fss = waveReduceSum(fe * fe);
        __syncthreads();                 // red1/redm reuse guard
        if (lane == 0) red1[wid] = fss;
        __syncthreads();
        const float fnorm = sqrtf(red1[0] + red1[1]);
        const float cross = uid_n * (fe / fmaxf(fnorm, 1e-12f));

        float km[MDIM];
        #pragma unroll
        for (int m = 0; m < MDIM; ++m) km[m] = cross * keyT[m * EDIM + t];
        #pragma unroll
        for (int s = 32; s >= 1; s >>= 1) {
            #pragma unroll
            for (int m = 0; m < MDIM; ++m) km[m] += __shfl_xor(km[m], s, 64);
        }
        if (lane == 0) {
            #pragma unroll
            for (int m = 0; m < MDIM; ++m) redm[wid * MDIM + m] = km[m];
        }
        __syncthreads();
        if (t < MDIM)
            att_key[((size_t)b * NFR + f) * MDIM + t] = redm[t] + redm[MDIM + t];
    }
}

// Kernel 2: per (f,m), max over b and sum_b exp(x - max)
__global__ __launch_bounds__(256)
void k2_stats(const float* __restrict__ att_key,
              float* __restrict__ mx,
              float* __restrict__ se,
              int B)
{
    const int f = blockIdx.x;
    const int t = threadIdx.x;
    const int m = t & (MDIM - 1);
    const int bg = t >> 3;            // 0..31
    __shared__ float red[256];

    float vmax = -3.4e38f;
    for (int b = bg; b < B; b += 32)
        vmax = fmaxf(vmax, att_key[((size_t)b * NFR + f) * MDIM + m]);
    red[t] = vmax;
    __syncthreads();
    for (int s = 128; s >= MDIM; s >>= 1) {
        if (t < s) red[t] = fmaxf(red[t], red[t + s]);
        __syncthreads();
    }
    const float fm = red[m];
    __syncthreads();

    float vsum = 0.0f;
    for (int b = bg; b < B; b += 32)
        vsum += __expf(att_key[((size_t)b * NFR + f) * MDIM + m] - fm);
    red[t] = vsum;
    __syncthreads();
    for (int s = 128; s >= MDIM; s >>= 1) {
        if (t < s) red[t] += red[t + s];
        __syncthreads();
    }
    if (t < MDIM) {
        mx[f * MDIM + t] = fm;      // for t<8, fm == max for m=t
        se[f * MDIM + t] = red[t];
    }
}

// Kernel 3: att_mem -> f1 -> f2 -> h -> j -> w -> friend -> score
__global__ __launch_bounds__(128)
void k3_final(const int* __restrict__ input_u,
              const int* __restrict__ input_i,
              const int* __restrict__ input_uf,
              const float* __restrict__ uidW,
              const float* __restrict__ iidW,
              const float* __restrict__ i_bias,
              const float* __restrict__ Mem,
              const float* __restrict__ WA,
              const float* __restrict__ BA,
              const float* __restrict__ U_omega,
              const float* __restrict__ att_key,
              const float* __restrict__ mx,
              const float* __restrict__ se,
              float* __restrict__ out,
              int user_num)
{
    const int b = blockIdx.x;
    const int t = threadIdx.x;      // == e
    const int wid = t >> 6, lane = t & 63;

    __shared__ float memL[MDIM * EDIM];   // [m][e]
    __shared__ float f2L[NFR * EDIM];     // [f][e] 25.6 KB
    __shared__ float jL[NFR];
    __shared__ float hpart[128];
    __shared__ float red1[2];

    for (int i = t; i < MDIM * EDIM; i += 128) memL[i] = Mem[i];

    const int* uf = input_uf + (size_t)b * NFR;
    const float* akb = att_key + (size_t)b * NFR * MDIM;

    __syncthreads();   // memL visible

    for (int f = 0; f < NFR; ++f) {
        const int fid = uf[f];
        const float fn = (fid != user_num) ? 1.0f : 0.0f;
        const float fe = uidW[(size_t)fid * EDIM + t] * fn;

        float f1 = 0.0f;
        #pragma unroll
        for (int m = 0; m < MDIM; ++m) {
            float ak = akb[f * MDIM + m];
            float am = fn * __expf(ak - mx[f * MDIM + m]) / se[f * MDIM + m];
            f1 += am * memL[m * EDIM + t];
        }
        const float f2 = f1 * fe;
        f2L[f * EDIM + t] = f2;
        __syncthreads();

        // h partials: thread t -> (a = t&63, half = t>>6)
        const int a = t & 63;
        const int half = t >> 6;
        const float* f2row = &f2L[f * EDIM + half * 64];
        const float* wa = WA + (size_t)(half * 64) * ADIM + a;
        float hp = 0.0f;
        #pragma unroll 8
        for (int e = 0; e < 64; ++e) hp += f2row[e] * wa[(size_t)e * ADIM];
        hpart[t] = hp;
        __syncthreads();

        if (t < ADIM) {                       // wave 0 only, full wave active
            float h = fmaxf(hpart[t] + hpart[t + 64] + BA[t], 0.0f);
            float p = waveReduceSum(h * U_omega[t]);
            if (t == 0) jL[f] = fn * __expf(p);
        }
        __syncthreads();                      // hpart reuse guard + jL publish
    }

    float wsum = 1e-8f;
    for (int f = 0; f < NFR; ++f) wsum += jL[f];
    float acc = 0.0f;
    for (int f = 0; f < NFR; ++f) acc += jL[f] * f2L[f * EDIM + t];
    const float friend_e = acc / wsum;

    const float uid_e = uidW[(size_t)input_u[b] * EDIM + t];
    const int ii = input_i[b];
    const float iid_e = iidW[(size_t)ii * EDIM + t];
    float prod = waveReduceSum((uid_e + friend_e) * iid_e);
    if (lane == 0) red1[wid] = prod;
    __syncthreads();
    if (t == 0) out[b] = red1[0] + red1[1] + i_bias[ii];
}

extern "C" void kernel_launch(void* const* d_in, const int* in_sizes, int n_in,
                              void* d_out, int out_size, void* d_ws, size_t ws_size,
                              hipStream_t stream)
{
    const int*   input_u  = (const int*)d_in[0];
    const int*   input_i  = (const int*)d_in[1];
    const int*   input_uf = (const int*)d_in[2];
    const float* uidW     = (const float*)d_in[3];
    const float* iidW     = (const float*)d_in[4];
    const float* i_bias   = (const float*)d_in[5];
    const float* Key      = (const float*)d_in[6];
    const float* Mem      = (const float*)d_in[7];
    const float* WA       = (const float*)d_in[8];
    const float* BA       = (const float*)d_in[9];
    const float* U_om     = (const float*)d_in[10];

    const int B = in_sizes[0];
    const int user_num = in_sizes[3] / EDIM - 1;

    float* att_key = (float*)d_ws;
    float* mx = att_key + (size_t)B * NFR * MDIM;
    float* se = mx + NFR * MDIM;

    k1_attkey<<<B, 128, 0, stream>>>(input_u, input_uf, uidW, Key, att_key, user_num);
    k2_stats<<<NFR, 256, 0, stream>>>(att_key, mx, se, B);
    k3_final<<<B, 128, 0, stream>>>(input_u, input_i, input_uf, uidW, iidW, i_bias,
                                    Mem, WA, BA, U_om, att_key, mx, se,
                                    (float*)d_out, user_num);
}

// Round 2
// 396.796 us; speedup vs baseline: 2.2180x; 2.2180x over previous
//
#include <hip/hip_runtime.h>

#define EDIM 128
#define MDIM 8
#define ADIM 64
#define NFR  50

__device__ __forceinline__ float waveReduceSum(float v) {
    #pragma unroll
    for (int s = 32; s >= 1; s >>= 1) v += __shfl_xor(v, s, 64);
    return v;
}

// Kernel 1: att_key[b,f,m] = sum_e (uid_n * fe_n)[e] * Key[e,m]
// Block = 256 thr = 4 waves; wave w handles friends f = w, w+4, ...
// Lane l holds e = l and e = l+64. No barriers in the friend loop.
__global__ __launch_bounds__(256, 8)
void k1_attkey(const int* __restrict__ input_u,
               const int* __restrict__ input_uf,
               const float* __restrict__ uidW,
               const float* __restrict__ Key,
               float* __restrict__ att_key,
               int user_num)
{
    const int b = blockIdx.x;
    const int t = threadIdx.x;
    const int w = t >> 6;
    const int l = t & 63;

    __shared__ float keyT[MDIM][EDIM];   // [m][e]
    for (int i = t; i < MDIM * EDIM; i += 256) {
        int m = i >> 7, e = i & 127;
        keyT[m][e] = Key[e * MDIM + m];
    }

    const int u = input_u[b];
    float u0 = uidW[(size_t)u * EDIM + l];
    float u1 = uidW[(size_t)u * EDIM + 64 + l];
    float ss = waveReduceSum(u0 * u0 + u1 * u1);
    float uinv = 1.0f / fmaxf(sqrtf(ss), 1e-12f);
    u0 *= uinv; u1 *= uinv;

    __syncthreads();   // keyT visible

    const int* uf = input_uf + (size_t)b * NFR;
    // precompute output m index for this lane's fold result
    const int mIdx = ((l & 1) << 2) | (l & 2) | ((l & 4) >> 2);

    for (int f = w; f < NFR; f += 4) {
        const int fid = uf[f];
        const float fn = (fid != user_num) ? 1.0f : 0.0f;
        float e0 = uidW[(size_t)fid * EDIM + l] * fn;
        float e1 = uidW[(size_t)fid * EDIM + 64 + l] * fn;
        float fss = waveReduceSum(e0 * e0 + e1 * e1);
        float finv = 1.0f / fmaxf(sqrtf(fss), 1e-12f);
        const float c0 = u0 * (e0 * finv);
        const float c1 = u1 * (e1 * finv);

        float v[MDIM];
        #pragma unroll
        for (int m = 0; m < MDIM; ++m)
            v[m] = c0 * keyT[m][l] + c1 * keyT[m][64 + l];

        // fold 8 values -> 1 per lane (m = mIdx), then butterfly over groups
        const bool b0m = (l & 1), b1m = (l & 2), b2m = (l & 4);
        #pragma unroll
        for (int k = 0; k < 4; ++k) {
            float lo = v[k], hi = v[k + 4];
            float send = b0m ? lo : hi;
            float recv = __shfl_xor(send, 1, 64);
            v[k] = b0m ? (hi + recv) : (lo + recv);
        }
        #pragma unroll
        for (int k = 0; k < 2; ++k) {
            float lo = v[k], hi = v[k + 2];
            float send = b1m ? lo : hi;
            float recv = __shfl_xor(send, 2, 64);
            v[k] = b1m ? (hi + recv) : (lo + recv);
        }
        {
            float lo = v[0], hi = v[1];
            float send = b2m ? lo : hi;
            float recv = __shfl_xor(send, 4, 64);
            v[0] = b2m ? (hi + recv) : (lo + recv);
        }
        v[0] += __shfl_xor(v[0], 8, 64);
        v[0] += __shfl_xor(v[0], 16, 64);
        v[0] += __shfl_xor(v[0], 32, 64);

        if (l < 8)
            att_key[((size_t)b * NFR + f) * MDIM + mIdx] = v[0];
    }
}

// Kernel 2: per (f,m), max over b and sum_b exp(x - max)
__global__ __launch_bounds__(256)
void k2_stats(const float* __restrict__ att_key,
              float* __restrict__ mx,
              float* __restrict__ se,
              int B)
{
    const int f = blockIdx.x;
    const int t = threadIdx.x;
    const int m = t & (MDIM - 1);
    const int bg = t >> 3;
    __shared__ float red[256];

    float vmax = -3.4e38f;
    for (int b = bg; b < B; b += 32)
        vmax = fmaxf(vmax, att_key[((size_t)b * NFR + f) * MDIM + m]);
    red[t] = vmax;
    __syncthreads();
    for (int s = 128; s >= MDIM; s >>= 1) {
        if (t < s) red[t] = fmaxf(red[t], red[t + s]);
        __syncthreads();
    }
    const float fm = red[m];
    __syncthreads();

    float vsum = 0.0f;
    for (int b = bg; b < B; b += 32)
        vsum += __expf(att_key[((size_t)b * NFR + f) * MDIM + m] - fm);
    red[t] = vsum;
    __syncthreads();
    for (int s = 128; s >= MDIM; s >>= 1) {
        if (t < s) red[t] += red[t + s];
        __syncthreads();
    }
    if (t < MDIM) {
        mx[f * MDIM + t] = fm;
        se[f * MDIM + t] = red[t];
    }
}

// Kernel 3: att_mem -> f1 -> f2 -> h -> j -> accumulate friend -> score.
// Wave-autonomous, friend PAIRS to amortize WA loads; no f2L[50][128].
__global__ __launch_bounds__(256, 4)
void k3_final(const int* __restrict__ input_u,
              const int* __restrict__ input_i,
              const int* __restrict__ input_uf,
              const float* __restrict__ uidW,
              const float* __restrict__ iidW,
              const float* __restrict__ i_bias,
              const float* __restrict__ Mem,
              const float* __restrict__ WA,
              const float* __restrict__ BA,
              const float* __restrict__ U_omega,
              const float* __restrict__ att_key,
              const float* __restrict__ mx,
              const float* __restrict__ se,
              float* __restrict__ out,
              int user_num)
{
    const int b = blockIdx.x;
    const int t = threadIdx.x;
    const int w = t >> 6;
    const int l = t & 63;

    __shared__ float memL[MDIM][EDIM];     // 4 KB
    __shared__ float stg[4][2][EDIM];      // 4 KB, per-wave f2 staging (A,B)
    __shared__ float accL[4][EDIM];        // 2 KB
    __shared__ float wsL[4];
    __shared__ float red2[2];

    for (int i = t; i < MDIM * EDIM; i += 256)
        memL[i >> 7][i & 127] = Mem[i];
    __syncthreads();

    const int* uf = input_uf + (size_t)b * NFR;
    const float ba = BA[l];
    const float uo = U_omega[l];

    float acc0 = 0.0f, acc1 = 0.0f, wsum = 0.0f;

    for (int f = w; f < NFR; f += 8) {
        const int fA = f;
        const int fB = f + 4;
        const bool hasB = (fB < NFR);
        const int fidA = uf[fA];
        const int fidB = hasB ? uf[fB] : user_num;
        const float fnA = (fidA != user_num) ? 1.0f : 0.0f;
        const float fnB = (hasB && fidB != user_num) ? 1.0f : 0.0f;
        const int fBc = hasB ? fB : fA;

        // f2 for A
        float a0, a1;
        {
            float fe0 = uidW[(size_t)fidA * EDIM + l] * fnA;
            float fe1 = uidW[(size_t)fidA * EDIM + 64 + l] * fnA;
            const float* ak = att_key + ((size_t)b * NFR + fA) * MDIM;
            float f10 = 0.0f, f11 = 0.0f;
            #pragma unroll
            for (int m = 0; m < MDIM; ++m) {
                float am = fnA * __expf(ak[m] - mx[fA * MDIM + m]) / se[fA * MDIM + m];
                f10 += am * memL[m][l];
                f11 += am * memL[m][64 + l];
            }
            a0 = f10 * fe0; a1 = f11 * fe1;
        }
        // f2 for B
        float b0, b1;
        {
            float fe0 = uidW[(size_t)fidB * EDIM + l] * fnB;
            float fe1 = uidW[(size_t)fidB * EDIM + 64 + l] * fnB;
            const float* ak = att_key + ((size_t)b * NFR + fBc) * MDIM;
            float f10 = 0.0f, f11 = 0.0f;
            #pragma unroll
            for (int m = 0; m < MDIM; ++m) {
                float am = fnB * __expf(ak[m] - mx[fBc * MDIM + m]) / se[fBc * MDIM + m];
                f10 += am * memL[m][l];
                f11 += am * memL[m][64 + l];
            }
            b0 = f10 * fe0; b1 = f11 * fe1;
        }

        stg[w][0][l] = a0; stg[w][0][64 + l] = a1;
        stg[w][1][l] = b0; stg[w][1][64 + l] = b1;
        // same-wave LDS RAW: compiler inserts lgkmcnt wait; no barrier needed

        // h[a=l] = sum_e f2[e]*WA[e][l]  for both friends
        float hA = 0.0f, hB = 0.0f;
        const float* wap = WA + l;
        #pragma unroll 8
        for (int e = 0; e < EDIM; e += 4) {
            float4 A4 = *(const float4*)&stg[w][0][e];
            float4 B4 = *(const float4*)&stg[w][1][e];
            float w0 = wap[(size_t)(e + 0) * ADIM];
            float w1 = wap[(size_t)(e + 1) * ADIM];
            float w2 = wap[(size_t)(e + 2) * ADIM];
            float w3 = wap[(size_t)(e + 3) * ADIM];
            hA += A4.x * w0; hA += A4.y * w1; hA += A4.z * w2; hA += A4.w * w3;
            hB += B4.x * w0; hB += B4.y * w1; hB += B4.z * w2; hB += B4.w * w3;
        }

        float pA = fmaxf(hA + ba, 0.0f) * uo;
        float sA = waveReduceSum(pA);
        float jA = fnA * __expf(sA);
        acc0 += jA * a0; acc1 += jA * a1; wsum += jA;

        float pB = fmaxf(hB + ba, 0.0f) * uo;
        float sB = waveReduceSum(pB);
        float jB = fnB * __expf(sB);
        acc0 += jB * b0; acc1 += jB * b1; wsum += jB;
    }

    accL[w][l] = acc0; accL[w][64 + l] = acc1;
    if (l == 0) wsL[w] = wsum;
    __syncthreads();

    if (t < EDIM) {
        float fr = (accL[0][t] + accL[1][t] + accL[2][t] + accL[3][t])
                 / (wsL[0] + wsL[1] + wsL[2] + wsL[3] + 1e-8f);
        const int u = input_u[b];
        const int ii = input_i[b];
        float sc = (uidW[(size_t)u * EDIM + t] + fr) * iidW[(size_t)ii * EDIM + t];
        float p = waveReduceSum(sc);
        if ((t & 63) == 0) red2[t >> 6] = p;
    }
    __syncthreads();
    if (t == 0) out[b] = red2[0] + red2[1] + i_bias[input_i[b]];
}

extern "C" void kernel_launch(void* const* d_in, const int* in_sizes, int n_in,
                              void* d_out, int out_size, void* d_ws, size_t ws_size,
                              hipStream_t stream)
{
    const int*   input_u  = (const int*)d_in[0];
    const int*   input_i  = (const int*)d_in[1];
    const int*   input_uf = (const int*)d_in[2];
    const float* uidW     = (const float*)d_in[3];
    const float* iidW     = (const float*)d_in[4];
    const float* i_bias   = (const float*)d_in[5];
    const float* Key      = (const float*)d_in[6];
    const float* Mem      = (const float*)d_in[7];
    const float* WA       = (const float*)d_in[8];
    const float* BA       = (const float*)d_in[9];
    const float* U_om     = (const float*)d_in[10];

    const int B = in_sizes[0];
    const int user_num = in_sizes[3] / EDIM - 1;

    float* att_key = (float*)d_ws;
    float* mx = att_key + (size_t)B * NFR * MDIM;
    float* se = mx + NFR * MDIM;

    k1_attkey<<<B, 256, 0, stream>>>(input_u, input_uf, uidW, Key, att_key, user_num);
    k2_stats<<<NFR, 256, 0, stream>>>(att_key, mx, se, B);
    k3_final<<<B, 256, 0, stream>>>(input_u, input_i, input_uf, uidW, iidW, i_bias,
                                    Mem, WA, BA, U_om, att_key, mx, se,
                                    (float*)d_out, user_num);
}

// Round 3
// 227.774 us; speedup vs baseline: 3.8640x; 1.7421x over previous
//
#include <hip/hip_runtime.h>

#define EDIM 128
#define MDIM 8
#define ADIM 64
#define NFR  50

typedef __attribute__((ext_vector_type(8))) short short8;
typedef __attribute__((ext_vector_type(4))) float f32x4;

__device__ __forceinline__ float waveReduceSum(float v) {
    #pragma unroll
    for (int s = 32; s >= 1; s >>= 1) v += __shfl_xor(v, s, 64);
    return v;
}
__device__ __forceinline__ short f2bf(float x) {
    unsigned u = __float_as_uint(x);
    u += 0x7FFFu + ((u >> 16) & 1u);
    return (short)(u >> 16);
}
__device__ __forceinline__ float bf2f(short s) {
    return __uint_as_float(((unsigned)(unsigned short)s) << 16);
}
// A-fragment-linear LDS index (in shorts) for element (row r<64, k=e<128)
// layout: [Mt=r>>4][Kt=e>>5][lane = quad(e)*16 + (r&15)][j = e&7]
__device__ __forceinline__ int fragIdx(int r, int e) {
    return ((((r >> 4) << 2) | (e >> 5)) * 64 + ((e >> 3) & 3) * 16 + (r & 15)) * 8 + (e & 7);
}

// k0: pre-pack WA (B-frags for 4 N-tiles x 4 K-tiles) and Key (4 K-tiles, N pad 8->16 w/ 0)
__global__ __launch_bounds__(256)
void k0_prep(const float* __restrict__ WA, const float* __restrict__ Key,
             short* __restrict__ WAfrag, short* __restrict__ Keyfrag)
{
    int t = blockIdx.x * 256 + threadIdx.x;
    if (t < 1024) {                       // WA: t = Nt*256 + Kt*64 + lane
        int lane = t & 63;
        int Kt = (t >> 6) & 3;
        int Nt = t >> 8;
        int n  = Nt * 16 + (lane & 15);
        int k0 = Kt * 32 + (lane >> 4) * 8;
        short8 v;
        #pragma unroll
        for (int j = 0; j < 8; ++j) v[j] = f2bf(WA[(size_t)(k0 + j) * ADIM + n]);
        *(short8*)(WAfrag + (size_t)t * 8) = v;
    } else if (t < 1280) {                // Key: i = Kt*64 + lane
        int i = t - 1024;
        int lane = i & 63;
        int Kt = i >> 6;
        int n  = lane & 15;
        int k0 = Kt * 32 + (lane >> 4) * 8;
        short8 v;
        #pragma unroll
        for (int j = 0; j < 8; ++j)
            v[j] = (n < MDIM) ? f2bf(Key[(size_t)(k0 + j) * MDIM + n]) : (short)0;
        *(short8*)(Keyfrag + (size_t)i * 8) = v;
    }
}

// k1: att_key[b,f,m] via MFMA: cross(64x128 bf16) x Key(128x16) -> C rows=f, cols=m
__global__ __launch_bounds__(256, 4)
void k1_attkey(const int* __restrict__ input_u, const int* __restrict__ input_uf,
               const float* __restrict__ uidW, const short* __restrict__ Keyfrag,
               float* __restrict__ att_key, int user_num)
{
    const int b = blockIdx.x, t = threadIdx.x, w = t >> 6, l = t & 63;
    __shared__ short crossF[64 * EDIM];   // 16 KB

    const int u = input_u[b];
    float u0 = uidW[(size_t)u * EDIM + l];
    float u1 = uidW[(size_t)u * EDIM + 64 + l];
    float ss = waveReduceSum(u0 * u0 + u1 * u1);
    float uinv = 1.0f / fmaxf(sqrtf(ss), 1e-12f);
    u0 *= uinv; u1 *= uinv;

    const int* uf = input_uf + (size_t)b * NFR;
    #pragma unroll 2
    for (int f = w; f < NFR; f += 4) {
        const int fid = uf[f];
        const float fn = (fid != user_num) ? 1.0f : 0.0f;
        float e0 = uidW[(size_t)fid * EDIM + l] * fn;
        float e1 = uidW[(size_t)fid * EDIM + 64 + l] * fn;
        float fss = waveReduceSum(e0 * e0 + e1 * e1);
        float finv = 1.0f / fmaxf(sqrtf(fss), 1e-12f);
        crossF[fragIdx(f, l)]      = f2bf(u0 * (e0 * finv));
        crossF[fragIdx(f, l + 64)] = f2bf(u1 * (e1 * finv));
    }
    __syncthreads();

    // wave w computes M-tile w (rows w*16..w*16+15), all K
    f32x4 acc = {0.f, 0.f, 0.f, 0.f};
    #pragma unroll
    for (int Kt = 0; Kt < 4; ++Kt) {
        short8 a  = *(const short8*)&crossF[(((w << 2) | Kt) * 64 + l) * 8];
        short8 bf = *(const short8*)(Keyfrag + (size_t)((Kt * 64 + l)) * 8);
        acc = __builtin_amdgcn_mfma_f32_16x16x32_bf16(a, bf, acc, 0, 0, 0);
    }
    const int m = l & 15;
    if (m < MDIM) {
        const int fbase = w * 16 + (l >> 4) * 4;
        #pragma unroll
        for (int r = 0; r < 4; ++r) {
            int f = fbase + r;
            if (f < NFR) att_key[((size_t)b * NFR + f) * MDIM + m] = acc[r];
        }
    }
}

// k2: per (f,m) column: softmax over batch, written back IN PLACE (att_key -> att_mem)
__global__ __launch_bounds__(256)
void k2_softmax(float* __restrict__ ak, int B)
{
    const int fm = blockIdx.x;            // = f*8+m; element index = b*400 + fm
    const int t = threadIdx.x;
    __shared__ float red[256];
    const size_t stride = (size_t)NFR * MDIM;

    float vmax = -3.4e38f;
    for (int b = t; b < B; b += 256)
        vmax = fmaxf(vmax, ak[(size_t)b * stride + fm]);
    red[t] = vmax; __syncthreads();
    for (int s = 128; s >= 1; s >>= 1) {
        if (t < s) red[t] = fmaxf(red[t], red[t + s]);
        __syncthreads();
    }
    const float mx = red[0]; __syncthreads();

    float vsum = 0.f;
    for (int b = t; b < B; b += 256)
        vsum += __expf(ak[(size_t)b * stride + fm] - mx);
    red[t] = vsum; __syncthreads();
    for (int s = 128; s >= 1; s >>= 1) {
        if (t < s) red[t] += red[t + s];
        __syncthreads();
    }
    const float inv = 1.0f / red[0];
    for (int b = t; b < B; b += 256) {
        size_t i = (size_t)b * stride + fm;
        ak[i] = __expf(ak[i] - mx) * inv;
    }
}

// k3: f2 -> MFMA h -> p fold -> j -> weighted friend sum -> score
__global__ __launch_bounds__(256, 4)
void k3_final(const int* __restrict__ input_u, const int* __restrict__ input_i,
              const int* __restrict__ input_uf, const float* __restrict__ uidW,
              const float* __restrict__ iidW, const float* __restrict__ i_bias,
              const float* __restrict__ Mem, const short* __restrict__ WAfrag,
              const float* __restrict__ BA, const float* __restrict__ U_omega,
              const float* __restrict__ att_mem, float* __restrict__ out,
              int user_num)
{
    const int b = blockIdx.x, t = threadIdx.x, w = t >> 6, l = t & 63;
    __shared__ short f2b[64 * EDIM];      // 16 KB
    __shared__ float pPart[4 * 64];
    __shared__ float jL[64];
    __shared__ float accL[4][EDIM];
    __shared__ float red2[2];
    __shared__ float wsS;

    float mem0[MDIM], mem1[MDIM];         // Mem in registers, no LDS
    #pragma unroll
    for (int m = 0; m < MDIM; ++m) {
        mem0[m] = Mem[m * EDIM + l];
        mem1[m] = Mem[m * EDIM + 64 + l];
    }

    const int* uf = input_uf + (size_t)b * NFR;

    // phase 1: f2 (bf16) into A-frag layout
    #pragma unroll 2
    for (int f = w; f < NFR; f += 4) {
        const int fid = uf[f];
        const float fn = (fid != user_num) ? 1.0f : 0.0f;
        float fe0 = uidW[(size_t)fid * EDIM + l] * fn;
        float fe1 = uidW[(size_t)fid * EDIM + 64 + l] * fn;
        const float* am = att_mem + ((size_t)b * NFR + f) * MDIM;  // uniform -> s_load
        float f10 = 0.f, f11 = 0.f;
        #pragma unroll
        for (int m = 0; m < MDIM; ++m) {
            float a = am[m];
            f10 += a * mem0[m];
            f11 += a * mem1[m];
        }
        f2b[fragIdx(f, l)]      = f2bf(f10 * fe0);
        f2b[fragIdx(f, l + 64)] = f2bf(f11 * fe1);
    }
    __syncthreads();

    // phase 2: h = f2 x WA; wave w owns cols a = w*16 + (l&15)
    f32x4 acc[4];
    #pragma unroll
    for (int Mt = 0; Mt < 4; ++Mt) acc[Mt] = (f32x4){0.f, 0.f, 0.f, 0.f};
    #pragma unroll
    for (int Kt = 0; Kt < 4; ++Kt) {
        short8 bf = *(const short8*)(WAfrag + (size_t)(((w << 2) | Kt) * 64 + l) * 8);
        #pragma unroll
        for (int Mt = 0; Mt < 4; ++Mt) {
            short8 a = *(const short8*)&f2b[(((Mt << 2) | Kt) * 64 + l) * 8];
            acc[Mt] = __builtin_amdgcn_mfma_f32_16x16x32_bf16(a, bf, acc[Mt], 0, 0, 0);
        }
    }

    // phase 3: v[f-part] = relu(h+BA)*U_omega, fold 16 regs over 16 cols -> 1/lane
    const int aIdx = w * 16 + (l & 15);
    const float ba = BA[aIdx];
    const float uo = U_omega[aIdx];
    float v[16];
    #pragma unroll
    for (int Mt = 0; Mt < 4; ++Mt)
        #pragma unroll
        for (int r = 0; r < 4; ++r)
            v[Mt * 4 + r] = fmaxf(acc[Mt][r] + ba, 0.f) * uo;

    const bool c0 = l & 1, c1 = l & 2, c2 = l & 4, c3 = l & 8;
    #pragma unroll
    for (int k = 0; k < 8; ++k) {
        float lo = v[k], hi = v[k + 8];
        float send = c0 ? lo : hi;
        float recv = __shfl_xor(send, 1, 64);
        v[k] = c0 ? (hi + recv) : (lo + recv);
    }
    #pragma unroll
    for (int k = 0; k < 4; ++k) {
        float lo = v[k], hi = v[k + 4];
        float send = c1 ? lo : hi;
        float recv = __shfl_xor(send, 2, 64);
        v[k] = c1 ? (hi + recv) : (lo + recv);
    }
    #pragma unroll
    for (int k = 0; k < 2; ++k) {
        float lo = v[k], hi = v[k + 2];
        float send = c2 ? lo : hi;
        float recv = __shfl_xor(send, 4, 64);
        v[k] = c2 ? (hi + recv) : (lo + recv);
    }
    {
        float lo = v[0], hi = v[1];
        float send = c3 ? lo : hi;
        float recv = __shfl_xor(send, 8, 64);
        v[0] = c3 ? (hi + recv) : (lo + recv);
    }
    const int vIdx = ((l & 1) << 3) | ((l & 2) << 1) | ((l & 4) >> 1) | ((l & 8) >> 3);
    const int fLane = (vIdx >> 2) * 16 + (l >> 4) * 4 + (vIdx & 3);
    pPart[w * 64 + fLane] = v[0];
    __syncthreads();

    if (t < 64) {
        float p = pPart[t] + pPart[64 + t] + pPart[128 + t] + pPart[192 + t];
        float jv = 0.f;
        if (t < NFR && uf[t] != user_num) jv = __expf(p);
        jL[t] = jv;
        float wsum = waveReduceSum(jv);
        if (t == 0) wsS = wsum + 1e-8f;
    }
    __syncthreads();

    // phase 4: acc_e = sum_f j[f] * f2[f][e], f-chunked per wave
    {
        const int fbeg = w * 13;
        const int fend = min(NFR, fbeg + 13);
        float a0 = 0.f, a1 = 0.f;
        for (int f = fbeg; f < fend; ++f) {
            float jf = jL[f];
            a0 += jf * bf2f(f2b[fragIdx(f, l)]);
            a1 += jf * bf2f(f2b[fragIdx(f, l + 64)]);
        }
        accL[w][l] = a0; accL[w][64 + l] = a1;
    }
    __syncthreads();

    if (t < EDIM) {
        const float winv = 1.0f / wsS;
        float fr = (accL[0][t] + accL[1][t] + accL[2][t] + accL[3][t]) * winv;
        const int u = input_u[b];
        const int ii = input_i[b];
        float sc = (uidW[(size_t)u * EDIM + t] + fr) * iidW[(size_t)ii * EDIM + t];
        float p = waveReduceSum(sc);
        if ((t & 63) == 0) red2[t >> 6] = p;
    }
    __syncthreads();
    if (t == 0) out[b] = red2[0] + red2[1] + i_bias[input_i[b]];
}

extern "C" void kernel_launch(void* const* d_in, const int* in_sizes, int n_in,
                              void* d_out, int out_size, void* d_ws, size_t ws_size,
                              hipStream_t stream)
{
    const int*   input_u  = (const int*)d_in[0];
    const int*   input_i  = (const int*)d_in[1];
    const int*   input_uf = (const int*)d_in[2];
    const float* uidW     = (const float*)d_in[3];
    const float* iidW     = (const float*)d_in[4];
    const float* i_bias   = (const float*)d_in[5];
    const float* Key      = (const float*)d_in[6];
    const float* Mem      = (const float*)d_in[7];
    const float* WA       = (const float*)d_in[8];
    const float* BA       = (const float*)d_in[9];
    const float* U_om     = (const float*)d_in[10];

    const int B = in_sizes[0];
    const int user_num = in_sizes[3] / EDIM - 1;

    float* att = (float*)d_ws;                                  // B*50*8 floats
    short* WAfrag  = (short*)(att + (size_t)B * NFR * MDIM);    // 8192 shorts
    short* Keyfrag = WAfrag + 4 * 4 * 64 * 8;                   // 2048 shorts

    k0_prep<<<5, 256, 0, stream>>>(WA, Key, WAfrag, Keyfrag);
    k1_attkey<<<B, 256, 0, stream>>>(input_u, input_uf, uidW, Keyfrag, att, user_num);
    k2_softmax<<<NFR * MDIM, 256, 0, stream>>>(att, B);
    k3_final<<<B, 256, 0, stream>>>(input_u, input_i, input_uf, uidW, iidW, i_bias,
                                    Mem, WAfrag, BA, U_om, att,
                                    (float*)d_out, user_num);
}

// Round 4
// 194.591 us; speedup vs baseline: 4.5229x; 1.1705x over previous
//
#include <hip/hip_runtime.h>

#define EDIM 128
#define MDIM 8
#define ADIM 64
#define NFR  50
#define NCOL (NFR * MDIM)   // 400

typedef __attribute__((ext_vector_type(8))) short short8;
typedef __attribute__((ext_vector_type(4))) float f32x4;

__device__ __forceinline__ float waveReduceSum(float v) {
    #pragma unroll
    for (int s = 32; s >= 1; s >>= 1) v += __shfl_xor(v, s, 64);
    return v;
}
__device__ __forceinline__ short f2bf(float x) {
    unsigned u = __float_as_uint(x);
    u += 0x7FFFu + ((u >> 16) & 1u);
    return (short)(u >> 16);
}
__device__ __forceinline__ float bf2f(short s) {
    return __uint_as_float(((unsigned)(unsigned short)s) << 16);
}
// A-fragment-linear LDS index (in shorts) for element (row r<64, k=e<128)
__device__ __forceinline__ int fragIdx(int r, int e) {
    return ((((r >> 4) << 2) | (e >> 5)) * 64 + ((e >> 3) & 3) * 16 + (r & 15)) * 8 + (e & 7);
}

// k0: pre-pack WA (B-frags 4Nt x 4Kt) and Key (4Kt, N padded 8->16 with 0)
__global__ __launch_bounds__(256)
void k0_prep(const float* __restrict__ WA, const float* __restrict__ Key,
             short* __restrict__ WAfrag, short* __restrict__ Keyfrag)
{
    int t = blockIdx.x * 256 + threadIdx.x;
    if (t < 1024) {
        int lane = t & 63;
        int Kt = (t >> 6) & 3;
        int Nt = t >> 8;
        int n  = Nt * 16 + (lane & 15);
        int k0 = Kt * 32 + (lane >> 4) * 8;
        short8 v;
        #pragma unroll
        for (int j = 0; j < 8; ++j) v[j] = f2bf(WA[(size_t)(k0 + j) * ADIM + n]);
        *(short8*)(WAfrag + (size_t)t * 8) = v;
    } else if (t < 1280) {
        int i = t - 1024;
        int lane = i & 63;
        int Kt = i >> 6;
        int n  = lane & 15;
        int k0 = Kt * 32 + (lane >> 4) * 8;
        short8 v;
        #pragma unroll
        for (int j = 0; j < 8; ++j)
            v[j] = (n < MDIM) ? f2bf(Key[(size_t)(k0 + j) * MDIM + n]) : (short)0;
        *(short8*)(Keyfrag + (size_t)i * 8) = v;
    }
}

// k1: att_key[b,f,m] via MFMA: cross(64x128 bf16) x Key(128x16)
__global__ __launch_bounds__(256, 4)
void k1_attkey(const int* __restrict__ input_u, const int* __restrict__ input_uf,
               const float* __restrict__ uidW, const short* __restrict__ Keyfrag,
               float* __restrict__ att_key, int user_num)
{
    const int b = blockIdx.x, t = threadIdx.x, w = t >> 6, l = t & 63;
    __shared__ short crossF[64 * EDIM];

    const int u = input_u[b];
    float u0 = uidW[(size_t)u * EDIM + l];
    float u1 = uidW[(size_t)u * EDIM + 64 + l];
    float ss = waveReduceSum(u0 * u0 + u1 * u1);
    float uinv = 1.0f / fmaxf(sqrtf(ss), 1e-12f);
    u0 *= uinv; u1 *= uinv;

    const int* uf = input_uf + (size_t)b * NFR;
    #pragma unroll 2
    for (int f = w; f < NFR; f += 4) {
        const int fid = uf[f];
        const float fn = (fid != user_num) ? 1.0f : 0.0f;
        float e0 = uidW[(size_t)fid * EDIM + l] * fn;
        float e1 = uidW[(size_t)fid * EDIM + 64 + l] * fn;
        float fss = waveReduceSum(e0 * e0 + e1 * e1);
        float finv = 1.0f / fmaxf(sqrtf(fss), 1e-12f);
        crossF[fragIdx(f, l)]      = f2bf(u0 * (e0 * finv));
        crossF[fragIdx(f, l + 64)] = f2bf(u1 * (e1 * finv));
    }
    __syncthreads();

    f32x4 acc = {0.f, 0.f, 0.f, 0.f};
    #pragma unroll
    for (int Kt = 0; Kt < 4; ++Kt) {
        short8 a  = *(const short8*)&crossF[(((w << 2) | Kt) * 64 + l) * 8];
        short8 bf = *(const short8*)(Keyfrag + (size_t)((Kt * 64 + l)) * 8);
        acc = __builtin_amdgcn_mfma_f32_16x16x32_bf16(a, bf, acc, 0, 0, 0);
    }
    const int m = l & 15;
    if (m < MDIM) {
        const int fbase = w * 16 + (l >> 4) * 4;
        #pragma unroll
        for (int r = 0; r < 4; ++r) {
            int f = fbase + r;
            if (f < NFR) att_key[((size_t)b * NFR + f) * MDIM + m] = acc[r];
        }
    }
}

// k2a: per (row-chunk, col-group): partial (max, sumexp) per column.
// Block (cg, rc): threads c=t&15 -> 16 consecutive cols (64-B line), r=t>>4.
__global__ __launch_bounds__(256)
void k2a_stats(const float* __restrict__ ak,
               float* __restrict__ Pm, float* __restrict__ Ps, int B)
{
    const int cg = blockIdx.x;       // 0..24
    const int rc = blockIdx.y;       // 0..15
    const int t = threadIdx.x;
    const int c = t & 15, r = t >> 4;
    const int col = cg * 16 + c;
    const int base = rc * (B >> 4);  // 256-row chunk

    float x[16];
    #pragma unroll
    for (int k = 0; k < 16; ++k)
        x[k] = ak[(size_t)(base + k * 16 + r) * NCOL + col];
    float m = x[0];
    #pragma unroll
    for (int k = 1; k < 16; ++k) m = fmaxf(m, x[k]);
    float s = 0.f;
    #pragma unroll
    for (int k = 0; k < 16; ++k) s += __expf(x[k] - m);

    __shared__ float mL[16][17], sL[16][17];
    mL[r][c] = m; sL[r][c] = s;
    __syncthreads();
    if (t < 16) {
        float M = mL[0][t];
        #pragma unroll
        for (int rr = 1; rr < 16; ++rr) M = fmaxf(M, mL[rr][t]);
        float S = 0.f;
        #pragma unroll
        for (int rr = 0; rr < 16; ++rr) S += sL[rr][t] * __expf(mL[rr][t] - M);
        Pm[rc * NCOL + cg * 16 + t] = M;
        Ps[rc * NCOL + cg * 16 + t] = S;
    }
}

// k2b: merge 16 chunk partials per column -> mx, inv_se
__global__ __launch_bounds__(512)
void k2b_merge(const float* __restrict__ Pm, const float* __restrict__ Ps,
               float* __restrict__ mx, float* __restrict__ ise)
{
    int col = threadIdx.x;
    if (col >= NCOL) return;
    float M = -3.4e38f;
    #pragma unroll
    for (int rc = 0; rc < 16; ++rc) M = fmaxf(M, Pm[rc * NCOL + col]);
    float S = 0.f;
    #pragma unroll
    for (int rc = 0; rc < 16; ++rc) S += Ps[rc * NCOL + col] * __expf(Pm[rc * NCOL + col] - M);
    mx[col] = M;
    ise[col] = 1.0f / S;
}

// k3: softmax-apply (fused) -> f2 -> MFMA h -> p fold -> j -> friend sum -> score
__global__ __launch_bounds__(256, 4)
void k3_final(const int* __restrict__ input_u, const int* __restrict__ input_i,
              const int* __restrict__ input_uf, const float* __restrict__ uidW,
              const float* __restrict__ iidW, const float* __restrict__ i_bias,
              const float* __restrict__ Mem, const short* __restrict__ WAfrag,
              const float* __restrict__ BA, const float* __restrict__ U_omega,
              const float* __restrict__ att_key, const float* __restrict__ mx,
              const float* __restrict__ ise, float* __restrict__ out,
              int user_num)
{
    const int b = blockIdx.x, t = threadIdx.x, w = t >> 6, l = t & 63;
    __shared__ short f2b[64 * EDIM];      // 16 KB
    __shared__ float mxL[NCOL], iseL[NCOL];
    __shared__ float pPart[4 * 64];
    __shared__ float jL[64];
    __shared__ float accL[4][EDIM];
    __shared__ float red2[2];
    __shared__ float wsS;

    for (int i = t; i < NCOL; i += 256) { mxL[i] = mx[i]; iseL[i] = ise[i]; }

    float mem0[MDIM], mem1[MDIM];
    #pragma unroll
    for (int m = 0; m < MDIM; ++m) {
        mem0[m] = Mem[m * EDIM + l];
        mem1[m] = Mem[m * EDIM + 64 + l];
    }
    __syncthreads();

    const int* uf = input_uf + (size_t)b * NFR;

    // phase 1: f2 (bf16) into A-frag layout, softmax applied inline
    #pragma unroll 2
    for (int f = w; f < NFR; f += 4) {
        const int fid = uf[f];
        const float fn = (fid != user_num) ? 1.0f : 0.0f;
        float fe0 = uidW[(size_t)fid * EDIM + l] * fn;
        float fe1 = uidW[(size_t)fid * EDIM + 64 + l] * fn;
        const float* ak = att_key + ((size_t)b * NFR + f) * MDIM;  // wave-uniform
        float f10 = 0.f, f11 = 0.f;
        #pragma unroll
        for (int m = 0; m < MDIM; ++m) {
            float a = fn * __expf(ak[m] - mxL[f * MDIM + m]) * iseL[f * MDIM + m];
            f10 += a * mem0[m];
            f11 += a * mem1[m];
        }
        f2b[fragIdx(f, l)]      = f2bf(f10 * fe0);
        f2b[fragIdx(f, l + 64)] = f2bf(f11 * fe1);
    }
    __syncthreads();

    // phase 2: h = f2 x WA
    f32x4 acc[4];
    #pragma unroll
    for (int Mt = 0; Mt < 4; ++Mt) acc[Mt] = (f32x4){0.f, 0.f, 0.f, 0.f};
    #pragma unroll
    for (int Kt = 0; Kt < 4; ++Kt) {
        short8 bf = *(const short8*)(WAfrag + (size_t)(((w << 2) | Kt) * 64 + l) * 8);
        #pragma unroll
        for (int Mt = 0; Mt < 4; ++Mt) {
            short8 a = *(const short8*)&f2b[(((Mt << 2) | Kt) * 64 + l) * 8];
            acc[Mt] = __builtin_amdgcn_mfma_f32_16x16x32_bf16(a, bf, acc[Mt], 0, 0, 0);
        }
    }

    // phase 3: fold relu(h+BA)*U_omega over 16 cols -> per-friend p
    const int aIdx = w * 16 + (l & 15);
    const float ba = BA[aIdx];
    const float uo = U_omega[aIdx];
    float v[16];
    #pragma unroll
    for (int Mt = 0; Mt < 4; ++Mt)
        #pragma unroll
        for (int r = 0; r < 4; ++r)
            v[Mt * 4 + r] = fmaxf(acc[Mt][r] + ba, 0.f) * uo;

    const bool c0 = l & 1, c1 = l & 2, c2 = l & 4, c3 = l & 8;
    #pragma unroll
    for (int k = 0; k < 8; ++k) {
        float lo = v[k], hi = v[k + 8];
        float send = c0 ? lo : hi;
        float recv = __shfl_xor(send, 1, 64);
        v[k] = c0 ? (hi + recv) : (lo + recv);
    }
    #pragma unroll
    for (int k = 0; k < 4; ++k) {
        float lo = v[k], hi = v[k + 4];
        float send = c1 ? lo : hi;
        float recv = __shfl_xor(send, 2, 64);
        v[k] = c1 ? (hi + recv) : (lo + recv);
    }
    #pragma unroll
    for (int k = 0; k < 2; ++k) {
        float lo = v[k], hi = v[k + 2];
        float send = c2 ? lo : hi;
        float recv = __shfl_xor(send, 4, 64);
        v[k] = c2 ? (hi + recv) : (lo + recv);
    }
    {
        float lo = v[0], hi = v[1];
        float send = c3 ? lo : hi;
        float recv = __shfl_xor(send, 8, 64);
        v[0] = c3 ? (hi + recv) : (lo + recv);
    }
    const int vIdx = ((l & 1) << 3) | ((l & 2) << 1) | ((l & 4) >> 1) | ((l & 8) >> 3);
    const int fLane = (vIdx >> 2) * 16 + (l >> 4) * 4 + (vIdx & 3);
    pPart[w * 64 + fLane] = v[0];
    __syncthreads();

    if (t < 64) {
        float p = pPart[t] + pPart[64 + t] + pPart[128 + t] + pPart[192 + t];
        float jv = 0.f;
        if (t < NFR && uf[t] != user_num) jv = __expf(p);
        jL[t] = jv;
        float wsum = waveReduceSum(jv);
        if (t == 0) wsS = wsum + 1e-8f;
    }
    __syncthreads();

    // phase 4: acc_e = sum_f j[f] * f2[f][e]
    {
        const int fbeg = w * 13;
        const int fend = min(NFR, fbeg + 13);
        float a0 = 0.f, a1 = 0.f;
        for (int f = fbeg; f < fend; ++f) {
            float jf = jL[f];
            a0 += jf * bf2f(f2b[fragIdx(f, l)]);
            a1 += jf * bf2f(f2b[fragIdx(f, l + 64)]);
        }
        accL[w][l] = a0; accL[w][64 + l] = a1;
    }
    __syncthreads();

    if (t < EDIM) {
        const float winv = 1.0f / wsS;
        float fr = (accL[0][t] + accL[1][t] + accL[2][t] + accL[3][t]) * winv;
        const int u = input_u[b];
        const int ii = input_i[b];
        float sc = (uidW[(size_t)u * EDIM + t] + fr) * iidW[(size_t)ii * EDIM + t];
        float p = waveReduceSum(sc);
        if ((t & 63) == 0) red2[t >> 6] = p;
    }
    __syncthreads();
    if (t == 0) out[b] = red2[0] + red2[1] + i_bias[input_i[b]];
}

extern "C" void kernel_launch(void* const* d_in, const int* in_sizes, int n_in,
                              void* d_out, int out_size, void* d_ws, size_t ws_size,
                              hipStream_t stream)
{
    const int*   input_u  = (const int*)d_in[0];
    const int*   input_i  = (const int*)d_in[1];
    const int*   input_uf = (const int*)d_in[2];
    const float* uidW     = (const float*)d_in[3];
    const float* iidW     = (const float*)d_in[4];
    const float* i_bias   = (const float*)d_in[5];
    const float* Key      = (const float*)d_in[6];
    const float* Mem      = (const float*)d_in[7];
    const float* WA       = (const float*)d_in[8];
    const float* BA       = (const float*)d_in[9];
    const float* U_om     = (const float*)d_in[10];

    const int B = in_sizes[0];
    const int user_num = in_sizes[3] / EDIM - 1;

    float* att = (float*)d_ws;                                   // B*400
    float* Pm  = att + (size_t)B * NCOL;                         // 16*400
    float* Ps  = Pm + 16 * NCOL;                                 // 16*400
    float* mx  = Ps + 16 * NCOL;                                 // 400
    float* ise = mx + NCOL;                                      // 400
    short* WAfrag  = (short*)(ise + NCOL);                       // 8192
    short* Keyfrag = WAfrag + 4 * 4 * 64 * 8;                    // 2048

    k0_prep<<<5, 256, 0, stream>>>(WA, Key, WAfrag, Keyfrag);
    k1_attkey<<<B, 256, 0, stream>>>(input_u, input_uf, uidW, Keyfrag, att, user_num);
    k2a_stats<<<dim3(25, 16), 256, 0, stream>>>(att, Pm, Ps, B);
    k2b_merge<<<1, 512, 0, stream>>>(Pm, Ps, mx, ise);
    k3_final<<<B, 256, 0, stream>>>(input_u, input_i, input_uf, uidW, iidW, i_bias,
                                    Mem, WAfrag, BA, U_om, att, mx, ise,
                                    (float*)d_out, user_num);
}

// Round 5
// 172.671 us; speedup vs baseline: 5.0970x; 1.1269x over previous
//
#include <hip/hip_runtime.h>

#define EDIM 128
#define MDIM 8
#define ADIM 64
#define NFR  50
#define NCOL (NFR * MDIM)   // 400

typedef __attribute__((ext_vector_type(8))) short short8;
typedef __attribute__((ext_vector_type(4))) float f32x4;

__device__ __forceinline__ float waveReduceSum(float v) {
    #pragma unroll
    for (int s = 32; s >= 1; s >>= 1) v += __shfl_xor(v, s, 64);
    return v;
}
__device__ __forceinline__ short f2bf(float x) {
    unsigned u = __float_as_uint(x);
    u += 0x7FFFu + ((u >> 16) & 1u);
    return (short)(u >> 16);
}
__device__ __forceinline__ float bf2f(short s) {
    return __uint_as_float(((unsigned)(unsigned short)s) << 16);
}
// Swizzled A-frag layout. Block (Mt=r>>4, Kt=e>>5) of 512 shorts; within it,
// slot = lane ^ (quad<<1) (bijective -> MFMA-side b128 reads conflict-free;
// writer/reader (f,kgroup) pattern lands 8 distinct words/bank = min cycles).
__device__ __forceinline__ int fragOff(int r, int e) {   // e multiple of 8
    int q = (e >> 3) & 3;
    int slot = (q * 16 + (r & 15)) ^ (q << 1);
    int block = ((r >> 4) << 2) | (e >> 5);
    return (block * 64 + slot) * 8;
}
__device__ __forceinline__ int slotR(int l) { return l ^ (((l >> 4) & 3) << 1); }

// k0: pre-pack WA (B-frags 4Nt x 4Kt) and Key (4Kt, N padded 8->16 with 0)
__global__ __launch_bounds__(256)
void k0_prep(const float* __restrict__ WA, const float* __restrict__ Key,
             short* __restrict__ WAfrag, short* __restrict__ Keyfrag)
{
    int t = blockIdx.x * 256 + threadIdx.x;
    if (t < 1024) {
        int lane = t & 63;
        int Kt = (t >> 6) & 3;
        int Nt = t >> 8;
        int n  = Nt * 16 + (lane & 15);
        int k0 = Kt * 32 + (lane >> 4) * 8;
        short8 v;
        #pragma unroll
        for (int j = 0; j < 8; ++j) v[j] = f2bf(WA[(size_t)(k0 + j) * ADIM + n]);
        *(short8*)(WAfrag + (size_t)t * 8) = v;
    } else if (t < 1280) {
        int i = t - 1024;
        int lane = i & 63;
        int Kt = i >> 6;
        int n  = lane & 15;
        int k0 = Kt * 32 + (lane >> 4) * 8;
        short8 v;
        #pragma unroll
        for (int j = 0; j < 8; ++j)
            v[j] = (n < MDIM) ? f2bf(Key[(size_t)(k0 + j) * MDIM + n]) : (short)0;
        *(short8*)(Keyfrag + (size_t)i * 8) = v;
    }
}

// k1: att_key via MFMA. Thread (fl=t>>4, kg=t&15) owns friend fl+16*it, e=kg*8..+7.
__global__ __launch_bounds__(256, 4)
void k1_attkey(const int* __restrict__ input_u, const int* __restrict__ input_uf,
               const float* __restrict__ uidW, const short* __restrict__ Keyfrag,
               float* __restrict__ att_key, int user_num)
{
    const int b = blockIdx.x, t = threadIdx.x, w = t >> 6, l = t & 63;
    __shared__ short crossF[64 * EDIM];   // 16 KB
    __shared__ float uidnL[EDIM];
    __shared__ float redW[4];
    __shared__ int ufL[64];

    const int u = input_u[b];
    float x = (t < EDIM) ? uidW[(size_t)u * EDIM + t] : 0.f;
    float s = waveReduceSum(x * x);
    if (l == 0) redW[w] = s;
    if (t < NFR) ufL[t] = input_uf[(size_t)b * NFR + t];
    else if (t < 64) ufL[t] = user_num;
    __syncthreads();
    float uinv = 1.0f / fmaxf(sqrtf(redW[0] + redW[1] + redW[2] + redW[3]), 1e-12f);
    if (t < EDIM) uidnL[t] = x * uinv;
    __syncthreads();

    const int kg = t & 15, fl = t >> 4;
    const int e0 = kg * 8;
    float4 un0 = *(const float4*)&uidnL[e0];
    float4 un1 = *(const float4*)&uidnL[e0 + 4];

    #pragma unroll
    for (int it = 0; it < 4; ++it) {
        int f = fl + 16 * it;
        short8 outv = {0, 0, 0, 0, 0, 0, 0, 0};
        if (f < NFR) {
            int fid = ufL[f];
            float fn = (fid != user_num) ? 1.f : 0.f;
            const float* fp = uidW + (size_t)fid * EDIM + e0;
            float4 g0 = *(const float4*)fp;
            float4 g1 = *(const float4*)(fp + 4);
            g0.x *= fn; g0.y *= fn; g0.z *= fn; g0.w *= fn;
            g1.x *= fn; g1.y *= fn; g1.z *= fn; g1.w *= fn;
            float fss = g0.x*g0.x + g0.y*g0.y + g0.z*g0.z + g0.w*g0.w
                      + g1.x*g1.x + g1.y*g1.y + g1.z*g1.z + g1.w*g1.w;
            fss += __shfl_xor(fss, 1, 64);
            fss += __shfl_xor(fss, 2, 64);
            fss += __shfl_xor(fss, 4, 64);
            fss += __shfl_xor(fss, 8, 64);
            float inv = 1.0f / fmaxf(sqrtf(fss), 1e-12f);
            outv[0] = f2bf(un0.x * g0.x * inv);
            outv[1] = f2bf(un0.y * g0.y * inv);
            outv[2] = f2bf(un0.z * g0.z * inv);
            outv[3] = f2bf(un0.w * g0.w * inv);
            outv[4] = f2bf(un1.x * g1.x * inv);
            outv[5] = f2bf(un1.y * g1.y * inv);
            outv[6] = f2bf(un1.z * g1.z * inv);
            outv[7] = f2bf(un1.w * g1.w * inv);
        }
        *(short8*)&crossF[fragOff(f, e0)] = outv;
    }
    __syncthreads();

    f32x4 acc = {0.f, 0.f, 0.f, 0.f};
    const int sl = slotR(l);
    #pragma unroll
    for (int Kt = 0; Kt < 4; ++Kt) {
        short8 a  = *(const short8*)&crossF[(((w << 2) | Kt) * 64 + sl) * 8];
        short8 bf = *(const short8*)(Keyfrag + (size_t)((Kt * 64 + l)) * 8);
        acc = __builtin_amdgcn_mfma_f32_16x16x32_bf16(a, bf, acc, 0, 0, 0);
    }
    const int m = l & 15;
    if (m < MDIM) {
        const int fbase = w * 16 + (l >> 4) * 4;
        #pragma unroll
        for (int r = 0; r < 4; ++r) {
            int f = fbase + r;
            if (f < NFR) att_key[((size_t)b * NFR + f) * MDIM + m] = acc[r];
        }
    }
}

// k2a: per (row-chunk, col-group): partial (max, sumexp) per column.
__global__ __launch_bounds__(256)
void k2a_stats(const float* __restrict__ ak,
               float* __restrict__ Pm, float* __restrict__ Ps, int B)
{
    const int cg = blockIdx.x;       // 0..24
    const int rc = blockIdx.y;       // 0..15
    const int t = threadIdx.x;
    const int c = t & 15, r = t >> 4;
    const int col = cg * 16 + c;
    const int base = rc * (B >> 4);

    float x[16];
    #pragma unroll
    for (int k = 0; k < 16; ++k)
        x[k] = ak[(size_t)(base + k * 16 + r) * NCOL + col];
    float m = x[0];
    #pragma unroll
    for (int k = 1; k < 16; ++k) m = fmaxf(m, x[k]);
    float s = 0.f;
    #pragma unroll
    for (int k = 0; k < 16; ++k) s += __expf(x[k] - m);

    __shared__ float mL[16][17], sL[16][17];
    mL[r][c] = m; sL[r][c] = s;
    __syncthreads();
    if (t < 16) {
        float M = mL[0][t];
        #pragma unroll
        for (int rr = 1; rr < 16; ++rr) M = fmaxf(M, mL[rr][t]);
        float S = 0.f;
        #pragma unroll
        for (int rr = 0; rr < 16; ++rr) S += sL[rr][t] * __expf(mL[rr][t] - M);
        Pm[rc * NCOL + cg * 16 + t] = M;
        Ps[rc * NCOL + cg * 16 + t] = S;
    }
}

// k2b: merge 16 chunk partials per column -> mx, inv_se
__global__ __launch_bounds__(512)
void k2b_merge(const float* __restrict__ Pm, const float* __restrict__ Ps,
               float* __restrict__ mx, float* __restrict__ ise)
{
    int col = threadIdx.x;
    if (col >= NCOL) return;
    float M = -3.4e38f;
    #pragma unroll
    for (int rc = 0; rc < 16; ++rc) M = fmaxf(M, Pm[rc * NCOL + col]);
    float S = 0.f;
    #pragma unroll
    for (int rc = 0; rc < 16; ++rc) S += Ps[rc * NCOL + col] * __expf(Pm[rc * NCOL + col] - M);
    mx[col] = M;
    ise[col] = 1.0f / S;
}

// k3: am precompute -> f2 frag (b128) -> MFMA h -> fold -> j -> friend sum -> score
__global__ __launch_bounds__(256, 4)
void k3_final(const int* __restrict__ input_u, const int* __restrict__ input_i,
              const int* __restrict__ input_uf, const float* __restrict__ uidW,
              const float* __restrict__ iidW, const float* __restrict__ i_bias,
              const float* __restrict__ Mem, const short* __restrict__ WAfrag,
              const float* __restrict__ BA, const float* __restrict__ U_omega,
              const float* __restrict__ att_key, const float* __restrict__ mx,
              const float* __restrict__ ise, float* __restrict__ out,
              int user_num)
{
    const int b = blockIdx.x, t = threadIdx.x, w = t >> 6, l = t & 63;
    __shared__ short f2F[64 * EDIM];      // 16 KB
    __shared__ float amL[NCOL];
    __shared__ int ufL[64];
    __shared__ float pPart[4 * 64];
    __shared__ float jxL[64];
    __shared__ float accW[4][EDIM];
    __shared__ float red2[2];
    __shared__ float wsS;

    if (t < NFR) ufL[t] = input_uf[(size_t)b * NFR + t];
    else if (t < 64) ufL[t] = user_num;
    __syncthreads();

    for (int i = t; i < NCOL; i += 256) {
        float ak = att_key[(size_t)b * NCOL + i];
        amL[i] = (ufL[i >> 3] != user_num) ? __expf(ak - mx[i]) * ise[i] : 0.f;
    }

    const int kg = t & 15, fl = t >> 4;
    const int e0 = kg * 8;
    float4 mA[MDIM], mB[MDIM];            // Mem slice in regs, reused 4 passes
    #pragma unroll
    for (int m = 0; m < MDIM; ++m) {
        mA[m] = *(const float4*)&Mem[m * EDIM + e0];
        mB[m] = *(const float4*)&Mem[m * EDIM + e0 + 4];
    }
    __syncthreads();

    // phase 1: f2 (bf16) -> swizzled frag, one b128 write per (f, e-octet)
    #pragma unroll
    for (int it = 0; it < 4; ++it) {
        int f = fl + 16 * it;
        short8 outv = {0, 0, 0, 0, 0, 0, 0, 0};
        if (f < NFR) {
            int fid = ufL[f];
            float fn = (fid != user_num) ? 1.f : 0.f;
            const float* fp = uidW + (size_t)fid * EDIM + e0;
            float4 g0 = *(const float4*)fp;
            float4 g1 = *(const float4*)(fp + 4);
            float4 am0 = *(const float4*)&amL[f * 8];
            float4 am1 = *(const float4*)&amL[f * 8 + 4];
            float4 fa = {0.f, 0.f, 0.f, 0.f}, fb = {0.f, 0.f, 0.f, 0.f};
            #pragma unroll
            for (int m = 0; m < 4; ++m) {
                float c0 = (&am0.x)[m], c1 = (&am1.x)[m];
                fa.x += c0 * mA[m].x + c1 * mA[m + 4].x;
                fa.y += c0 * mA[m].y + c1 * mA[m + 4].y;
                fa.z += c0 * mA[m].z + c1 * mA[m + 4].z;
                fa.w += c0 * mA[m].w + c1 * mA[m + 4].w;
                fb.x += c0 * mB[m].x + c1 * mB[m + 4].x;
                fb.y += c0 * mB[m].y + c1 * mB[m + 4].y;
                fb.z += c0 * mB[m].z + c1 * mB[m + 4].z;
                fb.w += c0 * mB[m].w + c1 * mB[m + 4].w;
            }
            outv[0] = f2bf(fa.x * g0.x * fn);
            outv[1] = f2bf(fa.y * g0.y * fn);
            outv[2] = f2bf(fa.z * g0.z * fn);
            outv[3] = f2bf(fa.w * g0.w * fn);
            outv[4] = f2bf(fb.x * g1.x * fn);
            outv[5] = f2bf(fb.y * g1.y * fn);
            outv[6] = f2bf(fb.z * g1.z * fn);
            outv[7] = f2bf(fb.w * g1.w * fn);
        }
        *(short8*)&f2F[fragOff(f, e0)] = outv;
    }
    __syncthreads();

    // phase 2: h = f2 x WA
    const int sl = slotR(l);
    f32x4 acc[4];
    #pragma unroll
    for (int Mt = 0; Mt < 4; ++Mt) acc[Mt] = (f32x4){0.f, 0.f, 0.f, 0.f};
    #pragma unroll
    for (int Kt = 0; Kt < 4; ++Kt) {
        short8 bf = *(const short8*)(WAfrag + (size_t)(((w << 2) | Kt) * 64 + l) * 8);
        #pragma unroll
        for (int Mt = 0; Mt < 4; ++Mt) {
            short8 a = *(const short8*)&f2F[(((Mt << 2) | Kt) * 64 + sl) * 8];
            acc[Mt] = __builtin_amdgcn_mfma_f32_16x16x32_bf16(a, bf, acc[Mt], 0, 0, 0);
        }
    }

    // phase 3: fold relu(h+BA)*U_omega over 16 cols -> per-friend p
    const int aIdx = w * 16 + (l & 15);
    const float ba = BA[aIdx];
    const float uo = U_omega[aIdx];
    float v[16];
    #pragma unroll
    for (int Mt = 0; Mt < 4; ++Mt)
        #pragma unroll
        for (int r = 0; r < 4; ++r)
            v[Mt * 4 + r] = fmaxf(acc[Mt][r] + ba, 0.f) * uo;

    const bool c0 = l & 1, c1 = l & 2, c2 = l & 4, c3 = l & 8;
    #pragma unroll
    for (int k = 0; k < 8; ++k) {
        float lo = v[k], hi = v[k + 8];
        float send = c0 ? lo : hi;
        float recv = __shfl_xor(send, 1, 64);
        v[k] = c0 ? (hi + recv) : (lo + recv);
    }
    #pragma unroll
    for (int k = 0; k < 4; ++k) {
        float lo = v[k], hi = v[k + 4];
        float send = c1 ? lo : hi;
        float recv = __shfl_xor(send, 2, 64);
        v[k] = c1 ? (hi + recv) : (lo + recv);
    }
    #pragma unroll
    for (int k = 0; k < 2; ++k) {
        float lo = v[k], hi = v[k + 2];
        float send = c2 ? lo : hi;
        float recv = __shfl_xor(send, 4, 64);
        v[k] = c2 ? (hi + recv) : (lo + recv);
    }
    {
        float lo = v[0], hi = v[1];
        float send = c3 ? lo : hi;
        float recv = __shfl_xor(send, 8, 64);
        v[0] = c3 ? (hi + recv) : (lo + recv);
    }
    const int vIdx = ((l & 1) << 3) | ((l & 2) << 1) | ((l & 4) >> 1) | ((l & 8) >> 3);
    const int fLane = (vIdx >> 2) * 16 + (l >> 4) * 4 + (vIdx & 3);
    pPart[w * 64 + fLane] = v[0];
    __syncthreads();

    if (t < 64) {
        float p = pPart[t] + pPart[64 + t] + pPart[128 + t] + pPart[192 + t];
        float jv = 0.f;
        if (t < NFR && ufL[t] != user_num) jv = __expf(p);
        jxL[t] = jv;
        float wsum = waveReduceSum(jv);
        if (t == 0) wsS = wsum + 1e-8f;
    }
    __syncthreads();

    // phase 4: acc[e-octet] = sum_f j[f]*f2[f][e]; b128 reads (pad rows are zero)
    float pa[8] = {0.f, 0.f, 0.f, 0.f, 0.f, 0.f, 0.f, 0.f};
    #pragma unroll
    for (int it = 0; it < 4; ++it) {
        int f = fl + 16 * it;             // f<64; jxL=0 & f2F=0 for pads
        float jf = jxL[f];
        short8 vv = *(const short8*)&f2F[fragOff(f, e0)];
        #pragma unroll
        for (int j = 0; j < 8; ++j) pa[j] += jf * bf2f(vv[j]);
    }
    #pragma unroll
    for (int j = 0; j < 8; ++j) {
        pa[j] += __shfl_xor(pa[j], 16, 64);
        pa[j] += __shfl_xor(pa[j], 32, 64);
    }
    if (l < 16) {
        #pragma unroll
        for (int j = 0; j < 8; ++j) accW[w][l * 8 + j] = pa[j];
    }
    __syncthreads();

    if (t < EDIM) {
        const float winv = 1.0f / wsS;
        float fr = (accW[0][t] + accW[1][t] + accW[2][t] + accW[3][t]) * winv;
        const int u = input_u[b];
        const int ii = input_i[b];
        float sc = (uidW[(size_t)u * EDIM + t] + fr) * iidW[(size_t)ii * EDIM + t];
        float p = waveReduceSum(sc);
        if ((t & 63) == 0) red2[t >> 6] = p;
    }
    __syncthreads();
    if (t == 0) out[b] = red2[0] + red2[1] + i_bias[input_i[b]];
}

extern "C" void kernel_launch(void* const* d_in, const int* in_sizes, int n_in,
                              void* d_out, int out_size, void* d_ws, size_t ws_size,
                              hipStream_t stream)
{
    const int*   input_u  = (const int*)d_in[0];
    const int*   input_i  = (const int*)d_in[1];
    const int*   input_uf = (const int*)d_in[2];
    const float* uidW     = (const float*)d_in[3];
    const float* iidW     = (const float*)d_in[4];
    const float* i_bias   = (const float*)d_in[5];
    const float* Key      = (const float*)d_in[6];
    const float* Mem      = (const float*)d_in[7];
    const float* WA       = (const float*)d_in[8];
    const float* BA       = (const float*)d_in[9];
    const float* U_om     = (const float*)d_in[10];

    const int B = in_sizes[0];
    const int user_num = in_sizes[3] / EDIM - 1;

    float* att = (float*)d_ws;                                   // B*400
    float* Pm  = att + (size_t)B * NCOL;                         // 16*400
    float* Ps  = Pm + 16 * NCOL;                                 // 16*400
    float* mx  = Ps + 16 * NCOL;                                 // 400
    float* ise = mx + NCOL;                                      // 400
    short* WAfrag  = (short*)(ise + NCOL);                       // 8192
    short* Keyfrag = WAfrag + 4 * 4 * 64 * 8;                    // 2048

    k0_prep<<<5, 256, 0, stream>>>(WA, Key, WAfrag, Keyfrag);
    k1_attkey<<<B, 256, 0, stream>>>(input_u, input_uf, uidW, Keyfrag, att, user_num);
    k2a_stats<<<dim3(25, 16), 256, 0, stream>>>(att, Pm, Ps, B);
    k2b_merge<<<1, 512, 0, stream>>>(Pm, Ps, mx, ise);
    k3_final<<<B, 256, 0, stream>>>(input_u, input_i, input_uf, uidW, iidW, i_bias,
                                    Mem, WAfrag, BA, U_om, att, mx, ise,
                                    (float*)d_out, user_num);
}